// Round 1
// baseline (174.547 us; speedup 1.0000x reference)
//
#include <hip/hip_runtime.h>
#include <hip/hip_bf16.h>
#include <cstdint>

typedef __attribute__((ext_vector_type(4))) float f32x4;
typedef __attribute__((ext_vector_type(8))) short bf16x8;

__device__ __forceinline__ ushort f2bf(float f) {
  unsigned u = __builtin_bit_cast(unsigned, f);
  u += 0x7fffu + ((u >> 16) & 1u);
  return (ushort)(u >> 16);
}
__device__ __forceinline__ float bf2f(ushort h) {
  unsigned u = ((unsigned)h) << 16;
  return __builtin_bit_cast(float, u);
}

__device__ __forceinline__ void gload_lds16(const ushort* g, ushort* l) {
  __builtin_amdgcn_global_load_lds(
      (const __attribute__((address_space(1))) unsigned int*)g,
      (__attribute__((address_space(3))) unsigned int*)l, 16, 0, 0);
}

// ---------- kernel 0a: x fp32 -> bf16 ----------
__global__ __launch_bounds__(256) void cvt_x_kernel(const float4* __restrict__ x,
                                                    ushort4* __restrict__ xb, int n4) {
  int stride = gridDim.x * blockDim.x;
  for (int i = blockIdx.x * blockDim.x + threadIdx.x; i < n4; i += stride) {
    float4 f = x[i];
    ushort4 o;
    o.x = f2bf(f.x); o.y = f2bf(f.y); o.z = f2bf(f.z); o.w = f2bf(f.w);
    xb[i] = o;
  }
}

// ---------- kernel 0b: W_qkv [1024][1536] f32 -> Wt [1536][1024] bf16 ----------
__global__ __launch_bounds__(256) void transpose_w_kernel(const float* __restrict__ W,
                                                          ushort* __restrict__ Wt) {
  __shared__ float tile[32][33];
  int n0 = blockIdx.x * 32;
  int k0 = blockIdx.y * 32;
  int tx = threadIdx.x;  // 0..31
  int ty = threadIdx.y;  // 0..7
  #pragma unroll
  for (int p = 0; p < 4; ++p) {
    int k = k0 + ty + p * 8;
    tile[ty + p * 8][tx] = W[(size_t)k * 1536 + n0 + tx];
  }
  __syncthreads();
  #pragma unroll
  for (int p = 0; p < 4; ++p) {
    int n = n0 + ty + p * 8;
    Wt[(size_t)n * 1024 + k0 + tx] = f2bf(tile[tx][ty + p * 8]);
  }
}

// ---------- shared GEMM mainloop: C[128x128] tile, A [M][LDA] bf16, Bt [N][LDB] bf16 ----------
template <int LDA, int LDB, int K>
__device__ __forceinline__ void gemm_tile(const ushort* __restrict__ A,
                                          const ushort* __restrict__ Bt,
                                          int row0, int col0, f32x4 acc[4][4]) {
  __shared__ ushort lsA[128 * 64];
  __shared__ ushort lsB[128 * 64];
  const int tid = threadIdx.x;
  const int lane = tid & 63;
  const int wid = tid >> 6;
  const int wr = wid >> 1;
  const int wc = wid & 1;
  const int fr = lane & 15;
  const int fq = lane >> 4;
  const int sr = tid >> 3;        // 0..31 (staging row)
  const int sc = (tid & 7) * 8;   // staging col (8 bf16 = 16B per lane)
  const ushort* aSrc = A + (size_t)(row0 + sr) * LDA + sc;
  const ushort* bSrc = Bt + (size_t)(col0 + sr) * LDB + sc;
  ushort* aDst = lsA + tid * 8;
  ushort* bDst = lsB + tid * 8;

  for (int k0 = 0; k0 < K; k0 += 64) {
    __syncthreads();
    #pragma unroll
    for (int p = 0; p < 4; ++p) {
      gload_lds16(aSrc + (size_t)p * 32 * LDA + k0, aDst + p * 2048);
      gload_lds16(bSrc + (size_t)p * 32 * LDB + k0, bDst + p * 2048);
    }
    __syncthreads();
    #pragma unroll
    for (int ks = 0; ks < 2; ++ks) {
      bf16x8 av[4], bv[4];
      #pragma unroll
      for (int m = 0; m < 4; ++m)
        av[m] = *(const bf16x8*)&lsA[(wr * 64 + m * 16 + fr) * 64 + ks * 32 + fq * 8];
      #pragma unroll
      for (int n = 0; n < 4; ++n)
        bv[n] = *(const bf16x8*)&lsB[(wc * 64 + n * 16 + fr) * 64 + ks * 32 + fq * 8];
      #pragma unroll
      for (int m = 0; m < 4; ++m)
        #pragma unroll
        for (int n = 0; n < 4; ++n)
          acc[m][n] = __builtin_amdgcn_mfma_f32_16x16x32_bf16(av[m], bv[n], acc[m][n], 0, 0, 0);
    }
  }
}

// ---------- kernel 1: qkv = x @ Wqkv, elu+1 on q,k cols, bf16 out ----------
__global__ __launch_bounds__(256) void gemm_qkv_kernel(const ushort* __restrict__ xb,
                                                       const ushort* __restrict__ wt,
                                                       ushort* __restrict__ qkv) {
  f32x4 acc[4][4] = {};
  const int row0 = blockIdx.x * 128;
  const int col0 = blockIdx.y * 128;
  gemm_tile<1024, 1024, 1024>(xb, wt, row0, col0, acc);
  const int lane = threadIdx.x & 63;
  const int wid = threadIdx.x >> 6;
  const int wr = wid >> 1, wc = wid & 1;
  const int fr = lane & 15, fq = lane >> 4;
  #pragma unroll
  for (int m = 0; m < 4; ++m) {
    #pragma unroll
    for (int n = 0; n < 4; ++n) {
      const int c = col0 + wc * 64 + n * 16 + fr;
      #pragma unroll
      for (int j = 0; j < 4; ++j) {
        const int r = row0 + wr * 64 + m * 16 + fq * 4 + j;
        float v = acc[m][n][j];
        if (c < 1024) v = (v > 0.f) ? (v + 1.f) : __expf(v);  // elu(v)+1
        qkv[(size_t)r * 1536 + c] = f2bf(v);
      }
    }
  }
}

// ---------- kernel 2: context partials: part[split][bh][d][e] = sum_{rows in split} k*v ----------
__global__ __launch_bounds__(256) void ctx_kernel(const ushort* __restrict__ qkv,
                                                  float* __restrict__ part) {
  const int bh = blockIdx.x;     // 0..31
  const int split = blockIdx.y;  // 0..15
  const int b = bh >> 3, h = bh & 7;
  const int t = threadIdx.x;
  const int d0 = (t >> 4) * 4;
  const int e0 = (t & 15) * 4;
  __shared__ ushort ks[64][64];
  __shared__ ushort vs[64][64];
  float acc[4][4] = {};
  const int rowBase = b * 4096 + split * 256;
  for (int chunk = 0; chunk < 256; chunk += 64) {
    __syncthreads();
    #pragma unroll
    for (int p = 0; p < 2; ++p) {
      const int r = (t >> 3) + p * 32;
      const int c = (t & 7) * 8;
      const ushort* src = qkv + (size_t)(rowBase + chunk + r) * 1536;
      *(uint4*)&ks[r][c] = *(const uint4*)(src + 512 + h * 64 + c);
      *(uint4*)&vs[r][c] = *(const uint4*)(src + 1024 + h * 64 + c);
    }
    __syncthreads();
    for (int r = 0; r < 64; ++r) {
      ushort4 ku = *(const ushort4*)&ks[r][d0];
      ushort4 vu = *(const ushort4*)&vs[r][e0];
      float kk[4] = {bf2f(ku.x), bf2f(ku.y), bf2f(ku.z), bf2f(ku.w)};
      float vv[4] = {bf2f(vu.x), bf2f(vu.y), bf2f(vu.z), bf2f(vu.w)};
      #pragma unroll
      for (int i = 0; i < 4; ++i)
        #pragma unroll
        for (int j = 0; j < 4; ++j)
          acc[i][j] += kk[i] * vv[j];
    }
  }
  float* dst = part + ((size_t)split * 32 + bh) * 4096;
  #pragma unroll
  for (int i = 0; i < 4; ++i)
    #pragma unroll
    for (int j = 0; j < 4; ++j)
      dst[(d0 + i) * 64 + (e0 + j)] = acc[i][j];
}

// ---------- kernel 3: reduce partials ----------
__global__ __launch_bounds__(256) void ctx_reduce_kernel(const float* __restrict__ part,
                                                         float* __restrict__ ctx) {
  const int i = blockIdx.x * 256 + threadIdx.x;  // 131072 total
  float s = 0.f;
  #pragma unroll
  for (int sp = 0; sp < 16; ++sp) s += part[(size_t)sp * 131072 + i];
  ctx[i] = s;
}

// ---------- kernel 4: W_eff^T[b][m][h*64+d] = sum_e ctx[b,h,d,e]*Wout[h*64+e][m], bf16 ----------
__global__ __launch_bounds__(256) void weff_kernel(const float* __restrict__ ctx,
                                                   const float* __restrict__ Wout,
                                                   ushort* __restrict__ weff) {
  const int bh = blockIdx.x;  // b*8+h
  const int h = bh & 7;
  const int m0 = blockIdx.y * 128;
  const int t = threadIdx.x;
  __shared__ float cs[64 * 64];
  __shared__ float ws[64][128];
  #pragma unroll
  for (int p = 0; p < 4; ++p) {
    const int idx = p * 1024 + t * 4;
    *(float4*)&cs[idx] = *(const float4*)&ctx[(size_t)bh * 4096 + idx];
  }
  #pragma unroll
  for (int p = 0; p < 8; ++p) {
    const int e = (t >> 5) + p * 8;
    const int c = (t & 31) * 4;
    *(float4*)&ws[e][c] = *(const float4*)&Wout[(size_t)(h * 64 + e) * 1024 + m0 + c];
  }
  __syncthreads();
  const int m = t & 127;
  const int dh = (t >> 7) * 32;
  float acc[32] = {};
  for (int e = 0; e < 64; ++e) {
    const float w = ws[e][m];
    #pragma unroll
    for (int i = 0; i < 32; ++i)
      acc[i] += cs[(dh + i) * 64 + e] * w;
  }
  ushort* dst = weff + ((size_t)(bh >> 3) * 1024 + m0 + m) * 512 + h * 64 + dh;
  #pragma unroll
  for (int i = 0; i < 32; ++i) dst[i] = f2bf(acc[i]);
}

// ---------- kernel 5: out = q @ W_eff^T + b_out (fp32 out) ----------
__global__ __launch_bounds__(256) void gemm_out_kernel(const ushort* __restrict__ qkv,
                                                       const ushort* __restrict__ weff,
                                                       const float* __restrict__ bout,
                                                       float* __restrict__ out) {
  f32x4 acc[4][4] = {};
  const int row0 = blockIdx.x * 128;
  const int col0 = blockIdx.y * 128;
  const int b = row0 >> 12;  // row0 / 4096
  gemm_tile<1536, 512, 512>(qkv, weff + (size_t)b * 1024 * 512, row0, col0, acc);
  const int lane = threadIdx.x & 63;
  const int wid = threadIdx.x >> 6;
  const int wr = wid >> 1, wc = wid & 1;
  const int fr = lane & 15, fq = lane >> 4;
  #pragma unroll
  for (int m = 0; m < 4; ++m) {
    #pragma unroll
    for (int n = 0; n < 4; ++n) {
      const int c = col0 + wc * 64 + n * 16 + fr;
      const float bb = bout[c];
      #pragma unroll
      for (int j = 0; j < 4; ++j) {
        const int r = row0 + wr * 64 + m * 16 + fq * 4 + j;
        out[(size_t)r * 1024 + c] = acc[m][n][j] + bb;
      }
    }
  }
}

extern "C" void kernel_launch(void* const* d_in, const int* in_sizes, int n_in,
                              void* d_out, int out_size, void* d_ws, size_t ws_size,
                              hipStream_t stream) {
  const float* x    = (const float*)d_in[0];
  const float* Wqkv = (const float*)d_in[1];
  const float* Wout = (const float*)d_in[2];
  const float* bout = (const float*)d_in[3];
  float* out = (float*)d_out;
  char* ws = (char*)d_ws;

  // workspace layout (bytes)
  ushort* xb   = (ushort*)(ws);              // 16384*1024*2  = 33554432
  ushort* wt   = (ushort*)(ws + 33554432);   // 1536*1024*2   = 3145728
  ushort* qkv  = (ushort*)(ws + 36700160);   // 16384*1536*2  = 50331648
  float*  part = (float* )(ws + 87031808);   // 16*32*4096*4  = 8388608
  float*  ctx  = (float* )(ws + 95420416);   // 32*4096*4     = 524288
  ushort* weff = (ushort*)(ws + 95944704);   // 4*1024*512*2  = 4194304

  cvt_x_kernel<<<2048, 256, 0, stream>>>((const float4*)x, (ushort4*)xb, 16384 * 1024 / 4);
  transpose_w_kernel<<<dim3(48, 32), dim3(32, 8), 0, stream>>>(Wqkv, wt);
  gemm_qkv_kernel<<<dim3(128, 12), 256, 0, stream>>>(xb, wt, qkv);
  ctx_kernel<<<dim3(32, 16), 256, 0, stream>>>(qkv, part);
  ctx_reduce_kernel<<<512, 256, 0, stream>>>(part, ctx);
  weff_kernel<<<dim3(32, 8), 256, 0, stream>>>(ctx, Wout, weff);
  gemm_out_kernel<<<dim3(128, 8), 256, 0, stream>>>(qkv, weff, bout, out);
}

// Round 2
// 150.666 us; speedup vs baseline: 1.1585x; 1.1585x over previous
//
#include <hip/hip_runtime.h>
#include <hip/hip_bf16.h>
#include <cstdint>

typedef __attribute__((ext_vector_type(4))) float f32x4;
typedef __attribute__((ext_vector_type(8))) short bf16x8;

__device__ __forceinline__ ushort f2bf(float f) {
  unsigned u = __builtin_bit_cast(unsigned, f);
  u += 0x7fffu + ((u >> 16) & 1u);
  return (ushort)(u >> 16);
}
__device__ __forceinline__ float bf2f(ushort h) {
  unsigned u = ((unsigned)h) << 16;
  return __builtin_bit_cast(float, u);
}

__device__ __forceinline__ void gload_lds16(const ushort* g, ushort* l) {
  __builtin_amdgcn_global_load_lds(
      (const __attribute__((address_space(1))) unsigned int*)g,
      (__attribute__((address_space(3))) unsigned int*)l, 16, 0, 0);
}

__device__ __forceinline__ void hard_barrier() {
  __builtin_amdgcn_sched_barrier(0);
  __builtin_amdgcn_s_barrier();
  __builtin_amdgcn_sched_barrier(0);
}

// ---------- kernel 0a: x fp32 -> bf16 ----------
__global__ __launch_bounds__(256) void cvt_x_kernel(const float4* __restrict__ x,
                                                    ushort4* __restrict__ xb, int n4) {
  int stride = gridDim.x * blockDim.x;
  for (int i = blockIdx.x * blockDim.x + threadIdx.x; i < n4; i += stride) {
    float4 f = x[i];
    ushort4 o;
    o.x = f2bf(f.x); o.y = f2bf(f.y); o.z = f2bf(f.z); o.w = f2bf(f.w);
    xb[i] = o;
  }
}

// ---------- kernel 0b: W_qkv [1024][1536] f32 -> Wt [1536][1024] bf16 ----------
__global__ __launch_bounds__(256) void transpose_w_kernel(const float* __restrict__ W,
                                                          ushort* __restrict__ Wt) {
  __shared__ float tile[32][33];
  int n0 = blockIdx.x * 32;
  int k0 = blockIdx.y * 32;
  int tx = threadIdx.x;  // 0..31
  int ty = threadIdx.y;  // 0..7
  #pragma unroll
  for (int p = 0; p < 4; ++p) {
    int k = k0 + ty + p * 8;
    tile[ty + p * 8][tx] = W[(size_t)k * 1536 + n0 + tx];
  }
  __syncthreads();
  #pragma unroll
  for (int p = 0; p < 4; ++p) {
    int n = n0 + ty + p * 8;
    Wt[(size_t)n * 1024 + k0 + tx] = f2bf(tile[tx][ty + p * 8]);
  }
}

// ============================================================================
// Deep-pipelined 128x256 GEMM core. 512 threads = 8 waves (2M x 4N), each wave
// owns a 64x64 output tile as 4x4 fragments of 16x16. BK=64, 3 LDS buffers
// (A 16KB + B 32KB = 48KB each; 144KB total), single raw s_barrier per K-tile,
// counted vmcnt(6) (6 global_load_lds per tile per thread), setprio on MFMA.
// LDS layout: linear dest for global_load_lds; bank-conflict-free reads via
// XOR swizzle applied to the per-lane GLOBAL source column (rule #21):
//   LDS[row][c] holds global col (c ^ ((row&7)*8)) for that row (ushort units).
// ============================================================================
template <int LDA, int LDB, int NT>
__device__ __forceinline__ void gemm_core(const ushort* __restrict__ A,
                                          const ushort* __restrict__ Bt,
                                          int row0, int col0, f32x4 acc[4][4],
                                          ushort* lds) {
  const int tid = threadIdx.x;
  const int l = tid & 63;
  const int wid = tid >> 6;
  const int fr = l & 15;
  const int fq = l >> 4;
  const int wr = wid >> 2;
  const int wc = wid & 3;

  // staging: thread handles row (tid>>3) + p*64, 16B column slot (tid&7),
  // source column pre-swizzled so that swizzled reads recover linear data.
  const int scol = ((l & 7) * 8) ^ (((l >> 3) & 7) * 8);  // ushort units
  const ushort* aS = A + (size_t)(row0 + (tid >> 3)) * LDA + scol;
  const ushort* bS = Bt + (size_t)(col0 + (tid >> 3)) * LDB + scol;

  // fragment read offsets (ushort units, within a buffer)
  int aRow[4], bRow[4], kx[2];
  #pragma unroll
  for (int m = 0; m < 4; ++m) aRow[m] = (wr * 64 + m * 16 + fr) * 64;
  #pragma unroll
  for (int n = 0; n < 4; ++n) bRow[n] = (wc * 64 + n * 16 + fr) * 64;
  #pragma unroll
  for (int ks = 0; ks < 2; ++ks) kx[ks] = (ks * 32 + fq * 8) ^ ((fr & 7) * 8);

  auto stage = [&](int t) {
    ushort* dst = lds + (t % 3) * 24576 + tid * 8;
    const int ko = t * 64;
    #pragma unroll
    for (int p = 0; p < 2; ++p)
      gload_lds16(aS + (size_t)(p * 64) * LDA + ko, dst + p * 4096);
    #pragma unroll
    for (int p = 0; p < 4; ++p)
      gload_lds16(bS + (size_t)(p * 64) * LDB + ko, dst + 8192 + p * 4096);
  };

  stage(0);
  stage(1);
  asm volatile("s_waitcnt vmcnt(6)" ::: "memory");  // stage(0) landed
  hard_barrier();

  #pragma unroll
  for (int t = 0; t < NT; ++t) {
    if (t + 2 < NT) stage(t + 2);  // targets buffer (t+2)%3 == (t-1)%3: free
    const ushort* aB = lds + (t % 3) * 24576;
    const ushort* bB = aB + 8192;
    #pragma unroll
    for (int ks = 0; ks < 2; ++ks) {
      bf16x8 av[4], bv[4];
      #pragma unroll
      for (int m = 0; m < 4; ++m) av[m] = *(const bf16x8*)&aB[aRow[m] + kx[ks]];
      #pragma unroll
      for (int n = 0; n < 4; ++n) bv[n] = *(const bf16x8*)&bB[bRow[n] + kx[ks]];
      __builtin_amdgcn_s_setprio(1);
      #pragma unroll
      for (int m = 0; m < 4; ++m)
        #pragma unroll
        for (int n = 0; n < 4; ++n)
          acc[m][n] = __builtin_amdgcn_mfma_f32_16x16x32_bf16(av[m], bv[n], acc[m][n], 0, 0, 0);
      __builtin_amdgcn_s_setprio(0);
    }
    if (t + 2 < NT) {
      asm volatile("s_waitcnt vmcnt(6)" ::: "memory");  // stage(t+1) landed
      hard_barrier();
    } else if (t + 1 < NT) {
      asm volatile("s_waitcnt vmcnt(0)" ::: "memory");  // tail: drain for last tile
      hard_barrier();
    }
  }
}

// ---------- kernel 1: qkv = x @ Wqkv, elu+1 on q,k cols, bf16 out ----------
__global__ __launch_bounds__(512, 2) void gemm_qkv_kernel(const ushort* __restrict__ xb,
                                                          const ushort* __restrict__ wt,
                                                          ushort* __restrict__ qkv) {
  __shared__ ushort lds[73728];  // 144 KiB
  f32x4 acc[4][4] = {};
  const int row0 = blockIdx.x * 128;
  const int col0 = blockIdx.y * 256;
  gemm_core<1024, 1024, 16>(xb, wt, row0, col0, acc, lds);
  const int l = threadIdx.x & 63;
  const int wid = threadIdx.x >> 6;
  const int wr = wid >> 2, wc = wid & 3;
  const int fr = l & 15, fq = l >> 4;
  #pragma unroll
  for (int m = 0; m < 4; ++m) {
    #pragma unroll
    for (int n = 0; n < 4; ++n) {
      const int c = col0 + wc * 64 + n * 16 + fr;
      #pragma unroll
      for (int j = 0; j < 4; ++j) {
        const int r = row0 + wr * 64 + m * 16 + fq * 4 + j;
        float v = acc[m][n][j];
        if (c < 1024) v = (v > 0.f) ? (v + 1.f) : __expf(v);  // elu(v)+1
        qkv[(size_t)r * 1536 + c] = f2bf(v);
      }
    }
  }
}

// ---------- kernel 2: context partials ----------
__global__ __launch_bounds__(256) void ctx_kernel(const ushort* __restrict__ qkv,
                                                  float* __restrict__ part) {
  const int bh = blockIdx.x;     // 0..31
  const int split = blockIdx.y;  // 0..15
  const int b = bh >> 3, h = bh & 7;
  const int t = threadIdx.x;
  const int d0 = (t >> 4) * 4;
  const int e0 = (t & 15) * 4;
  __shared__ ushort ks[64][64];
  __shared__ ushort vs[64][64];
  float acc[4][4] = {};
  const int rowBase = b * 4096 + split * 256;
  for (int chunk = 0; chunk < 256; chunk += 64) {
    __syncthreads();
    #pragma unroll
    for (int p = 0; p < 2; ++p) {
      const int r = (t >> 3) + p * 32;
      const int c = (t & 7) * 8;
      const ushort* src = qkv + (size_t)(rowBase + chunk + r) * 1536;
      *(uint4*)&ks[r][c] = *(const uint4*)(src + 512 + h * 64 + c);
      *(uint4*)&vs[r][c] = *(const uint4*)(src + 1024 + h * 64 + c);
    }
    __syncthreads();
    for (int r = 0; r < 64; ++r) {
      ushort4 ku = *(const ushort4*)&ks[r][d0];
      ushort4 vu = *(const ushort4*)&vs[r][e0];
      float kk[4] = {bf2f(ku.x), bf2f(ku.y), bf2f(ku.z), bf2f(ku.w)};
      float vv[4] = {bf2f(vu.x), bf2f(vu.y), bf2f(vu.z), bf2f(vu.w)};
      #pragma unroll
      for (int i = 0; i < 4; ++i)
        #pragma unroll
        for (int j = 0; j < 4; ++j)
          acc[i][j] += kk[i] * vv[j];
    }
  }
  float* dst = part + ((size_t)split * 32 + bh) * 4096;
  #pragma unroll
  for (int i = 0; i < 4; ++i)
    #pragma unroll
    for (int j = 0; j < 4; ++j)
      dst[(d0 + i) * 64 + (e0 + j)] = acc[i][j];
}

// ---------- kernel 3: reduce partials ----------
__global__ __launch_bounds__(256) void ctx_reduce_kernel(const float* __restrict__ part,
                                                         float* __restrict__ ctx) {
  const int i = blockIdx.x * 256 + threadIdx.x;  // 131072 total
  float s = 0.f;
  #pragma unroll
  for (int sp = 0; sp < 16; ++sp) s += part[(size_t)sp * 131072 + i];
  ctx[i] = s;
}

// ---------- kernel 4: W_eff^T ----------
__global__ __launch_bounds__(256) void weff_kernel(const float* __restrict__ ctx,
                                                   const float* __restrict__ Wout,
                                                   ushort* __restrict__ weff) {
  const int bh = blockIdx.x;  // b*8+h
  const int h = bh & 7;
  const int m0 = blockIdx.y * 128;
  const int t = threadIdx.x;
  __shared__ float cs[64 * 64];
  __shared__ float ws[64][128];
  #pragma unroll
  for (int p = 0; p < 4; ++p) {
    const int idx = p * 1024 + t * 4;
    *(float4*)&cs[idx] = *(const float4*)&ctx[(size_t)bh * 4096 + idx];
  }
  #pragma unroll
  for (int p = 0; p < 8; ++p) {
    const int e = (t >> 5) + p * 8;
    const int c = (t & 31) * 4;
    *(float4*)&ws[e][c] = *(const float4*)&Wout[(size_t)(h * 64 + e) * 1024 + m0 + c];
  }
  __syncthreads();
  const int m = t & 127;
  const int dh = (t >> 7) * 32;
  float acc[32] = {};
  for (int e = 0; e < 64; ++e) {
    const float w = ws[e][m];
    #pragma unroll
    for (int i = 0; i < 32; ++i)
      acc[i] += cs[(dh + i) * 64 + e] * w;
  }
  ushort* dst = weff + ((size_t)(bh >> 3) * 1024 + m0 + m) * 512 + h * 64 + dh;
  #pragma unroll
  for (int i = 0; i < 32; ++i) dst[i] = f2bf(acc[i]);
}

// ---------- kernel 5: out = q @ W_eff^T + b_out (fp32 out) ----------
__global__ __launch_bounds__(512, 2) void gemm_out_kernel(const ushort* __restrict__ qkv,
                                                          const ushort* __restrict__ weff,
                                                          const float* __restrict__ bout,
                                                          float* __restrict__ out) {
  __shared__ ushort lds[73728];  // 144 KiB
  f32x4 acc[4][4] = {};
  const int row0 = blockIdx.x * 128;
  const int col0 = blockIdx.y * 256;
  const int b = row0 >> 12;  // row0 / 4096
  gemm_core<1536, 512, 8>(qkv, weff + (size_t)b * 1024 * 512, row0, col0, acc, lds);
  const int l = threadIdx.x & 63;
  const int wid = threadIdx.x >> 6;
  const int wr = wid >> 2, wc = wid & 3;
  const int fr = l & 15, fq = l >> 4;
  #pragma unroll
  for (int m = 0; m < 4; ++m) {
    #pragma unroll
    for (int n = 0; n < 4; ++n) {
      const int c = col0 + wc * 64 + n * 16 + fr;
      const float bb = bout[c];
      #pragma unroll
      for (int j = 0; j < 4; ++j) {
        const int r = row0 + wr * 64 + m * 16 + fq * 4 + j;
        out[(size_t)r * 1024 + c] = acc[m][n][j] + bb;
      }
    }
  }
}

extern "C" void kernel_launch(void* const* d_in, const int* in_sizes, int n_in,
                              void* d_out, int out_size, void* d_ws, size_t ws_size,
                              hipStream_t stream) {
  const float* x    = (const float*)d_in[0];
  const float* Wqkv = (const float*)d_in[1];
  const float* Wout = (const float*)d_in[2];
  const float* bout = (const float*)d_in[3];
  float* out = (float*)d_out;
  char* ws = (char*)d_ws;

  // workspace layout (bytes)
  ushort* xb   = (ushort*)(ws);              // 16384*1024*2  = 33554432
  ushort* wt   = (ushort*)(ws + 33554432);   // 1536*1024*2   = 3145728
  ushort* qkv  = (ushort*)(ws + 36700160);   // 16384*1536*2  = 50331648
  float*  part = (float* )(ws + 87031808);   // 16*32*4096*4  = 8388608
  float*  ctx  = (float* )(ws + 95420416);   // 32*4096*4     = 524288
  ushort* weff = (ushort*)(ws + 95944704);   // 4*1024*512*2  = 4194304

  cvt_x_kernel<<<2048, 256, 0, stream>>>((const float4*)x, (ushort4*)xb, 16384 * 1024 / 4);
  transpose_w_kernel<<<dim3(48, 32), dim3(32, 8), 0, stream>>>(Wqkv, wt);
  gemm_qkv_kernel<<<dim3(128, 6), 512, 0, stream>>>(xb, wt, qkv);
  ctx_kernel<<<dim3(32, 16), 256, 0, stream>>>(qkv, part);
  ctx_reduce_kernel<<<512, 256, 0, stream>>>(part, ctx);
  weff_kernel<<<dim3(32, 8), 256, 0, stream>>>(ctx, Wout, weff);
  gemm_out_kernel<<<dim3(128, 4), 512, 0, stream>>>(qkv, weff, bout, out);
}